// Round 5
// baseline (1022.187 us; speedup 1.0000x reference)
//
#include <hip/hip_runtime.h>
#include <hip/hip_bf16.h>
#include <cstdint>
#include <cstddef>

#define D 128
#define NEG_SLOPE 0.2f

__device__ __forceinline__ float leaky(float x) { return x > 0.f ? x : NEG_SLOPE * x; }

// ---------------- CSR build ----------------

__global__ void gat_count_deg(const int* __restrict__ ei, int* __restrict__ cursor, int E) {
    int e = blockIdx.x * 256 + threadIdx.x;
    if (e < E) atomicAdd(&cursor[ei[E + e]], 1);
}

__global__ void gat_chunk_sum(const int* __restrict__ deg, int* __restrict__ partial, int n) {
    __shared__ int sm[256];
    int t = threadIdx.x, base = blockIdx.x * 512;
    int s = 0;
    if (base + t < n)       s += deg[base + t];
    if (base + 256 + t < n) s += deg[base + 256 + t];
    sm[t] = s; __syncthreads();
    for (int off = 128; off; off >>= 1) { if (t < off) sm[t] += sm[t + off]; __syncthreads(); }
    if (t == 0) partial[blockIdx.x] = sm[0];
}

// single block; assumes nchunks <= 256 (N=100000 -> 196 chunks)
__global__ void gat_scan_partials(const int* __restrict__ partial, int* __restrict__ chunkoff,
                                  int* __restrict__ rowptr, int nchunks, int n) {
    __shared__ int sm[256];
    int t = threadIdx.x;
    int v = (t < nchunks) ? partial[t] : 0;
    sm[t] = v; __syncthreads();
    for (int off = 1; off < 256; off <<= 1) {
        int x = (t >= off) ? sm[t - off] : 0;
        __syncthreads();
        sm[t] += x;
        __syncthreads();
    }
    chunkoff[t] = sm[t] - v;           // exclusive
    if (t == 255) rowptr[n] = sm[255]; // total edge count
}

__global__ void gat_chunk_scan(int* __restrict__ cursor, int* __restrict__ rowptr,
                               const int* __restrict__ chunkoff, int n) {
    __shared__ int sm[256];
    int t = threadIdx.x, base = blockIdx.x * 512;
    int i0 = base + 2 * t, i1 = i0 + 1;
    int d0 = (i0 < n) ? cursor[i0] : 0;
    int d1 = (i1 < n) ? cursor[i1] : 0;
    int s = d0 + d1;
    sm[t] = s; __syncthreads();
    for (int off = 1; off < 256; off <<= 1) {
        int x = (t >= off) ? sm[t - off] : 0;
        __syncthreads();
        sm[t] += x;
        __syncthreads();
    }
    int excl = sm[t] - s + chunkoff[blockIdx.x];
    if (i0 < n) { rowptr[i0] = excl;      cursor[i0] = excl; }
    if (i1 < n) { rowptr[i1] = excl + d0; cursor[i1] = excl + d0; }
}

__global__ void gat_scatter(const int* __restrict__ ei, int* __restrict__ cursor,
                            int* __restrict__ csr, int E) {
    int e = blockIdx.x * 256 + threadIdx.x;
    if (e < E) {
        int s = ei[e], d = ei[E + e];
        int p = atomicAdd(&cursor[d], 1);
        csr[p] = s;
    }
}

// ---------------- fp32 GEMM: H = A @ W, fused s_src/s_dst epilogue ----------------
// block: 256 threads; BM=64 rows x BN=128 (full width); BK=32
// thread (tn = t&15, tm = t>>4) computes rows tm*4..tm*4+3, cols tn*8..tn*8+7
__launch_bounds__(256)
__global__ void gat_gemm_s(const float* __restrict__ A, const float* __restrict__ W,
                           const float* __restrict__ aS, const float* __restrict__ aD,
                           float* __restrict__ H, float* __restrict__ sS, float* __restrict__ sD,
                           int n) {
    __shared__ float At[32][68];   // [k][row], padded, 16B-aligned rows
    __shared__ float Wt[32][136];  // [k][col], padded, 16B-aligned rows
    int t = threadIdx.x;
    int tn = t & 15, tm = t >> 4;
    int r0 = blockIdx.x * 64;

    float c[4][8];
#pragma unroll
    for (int r = 0; r < 4; ++r)
#pragma unroll
        for (int j = 0; j < 8; ++j) c[r][j] = 0.f;

    for (int k0 = 0; k0 < D; k0 += 32) {
        // A tile (64x32), stored transposed
        int row = t >> 3;
        int c4 = (t & 7) * 4;
#pragma unroll
        for (int h = 0; h < 2; ++h) {
            int rr = row + h * 32;
            int gr = r0 + rr;
            float4 v;
            if (gr < n) v = *(const float4*)&A[(size_t)gr * D + k0 + c4];
            else { v.x = v.y = v.z = v.w = 0.f; }
            At[c4 + 0][rr] = v.x; At[c4 + 1][rr] = v.y;
            At[c4 + 2][rr] = v.z; At[c4 + 3][rr] = v.w;
        }
        // W tile (32x128)
#pragma unroll
        for (int i = 0; i < 4; ++i) {
            int idx = t + i * 256;
            int k = idx >> 5;
            int cw = (idx & 31) * 4;
            *(float4*)&Wt[k][cw] = *(const float4*)&W[(size_t)(k0 + k) * D + cw];
        }
        __syncthreads();
#pragma unroll
        for (int kk = 0; kk < 32; ++kk) {
            float4 a4 = *(const float4*)&At[kk][tm * 4];
            float4 b0 = *(const float4*)&Wt[kk][tn * 8];
            float4 b1 = *(const float4*)&Wt[kk][tn * 8 + 4];
            float a_[4] = {a4.x, a4.y, a4.z, a4.w};
            float b_[8] = {b0.x, b0.y, b0.z, b0.w, b1.x, b1.y, b1.z, b1.w};
#pragma unroll
            for (int r = 0; r < 4; ++r)
#pragma unroll
                for (int j = 0; j < 8; ++j) c[r][j] += a_[r] * b_[j];
        }
        __syncthreads();
    }

    // epilogue: store H + per-row dot with a_src/a_dst
    float as_[8], ad_[8];
#pragma unroll
    for (int j = 0; j < 8; ++j) { as_[j] = aS[tn * 8 + j]; ad_[j] = aD[tn * 8 + j]; }
    float pS[4], pD[4];
#pragma unroll
    for (int r = 0; r < 4; ++r) {
        int gr = r0 + tm * 4 + r;
        pS[r] = 0.f; pD[r] = 0.f;
#pragma unroll
        for (int j = 0; j < 8; ++j) { pS[r] += as_[j] * c[r][j]; pD[r] += ad_[j] * c[r][j]; }
        if (gr < n) {
            float4 v0; v0.x = c[r][0]; v0.y = c[r][1]; v0.z = c[r][2]; v0.w = c[r][3];
            float4 v1; v1.x = c[r][4]; v1.y = c[r][5]; v1.z = c[r][6]; v1.w = c[r][7];
            *(float4*)&H[(size_t)gr * D + tn * 8]     = v0;
            *(float4*)&H[(size_t)gr * D + tn * 8 + 4] = v1;
        }
    }
#pragma unroll
    for (int off = 1; off < 16; off <<= 1) {
#pragma unroll
        for (int r = 0; r < 4; ++r) {
            pS[r] += __shfl_xor(pS[r], off);
            pD[r] += __shfl_xor(pD[r], off);
        }
    }
    if (tn == 0) {
#pragma unroll
        for (int r = 0; r < 4; ++r) {
            int gr = r0 + tm * 4 + r;
            if (gr < n) { sS[gr] = pS[r]; sD[gr] = pD[r]; }
        }
    }
}

// ---------------- aggregation: one wave per destination node ----------------
__launch_bounds__(256)
__global__ void gat_agg(const float* __restrict__ H, const int* __restrict__ rowptr,
                        const int* __restrict__ csr, const float* __restrict__ sS,
                        const float* __restrict__ sD, const float* __restrict__ b,
                        float* __restrict__ O, int n) {
    int v = blockIdx.x * 4 + (threadIdx.x >> 6);
    if (v >= n) return;
    int lane = threadIdx.x & 63;
    int st = rowptr[v], en = rowptr[v + 1];
    float sdv = sD[v];
    float aself = leaky(sS[v] + sdv);

    // pass 1: max (lane-parallel over edges)
    float m = aself;
    for (int i = st + lane; i < en; i += 64) {
        int u = csr[i];
        m = fmaxf(m, leaky(sS[u] + sdv));
    }
#pragma unroll
    for (int off = 32; off; off >>= 1) m = fmaxf(m, __shfl_xor(m, off));

    // pass 2: exp-sum
    float l = 0.f;
    for (int i = st + lane; i < en; i += 64) {
        int u = csr[i];
        l += __expf(leaky(sS[u] + sdv) - m);
    }
#pragma unroll
    for (int off = 32; off; off >>= 1) l += __shfl_xor(l, off);
    l += __expf(aself - m);

    // pass 3: channel-parallel weighted gather (lane -> 2 channels)
    int ch = lane * 2;
    float wv = __expf(aself - m);
    float2 h2 = *(const float2*)&H[(size_t)v * D + ch];
    float accx = wv * h2.x, accy = wv * h2.y;
    for (int i = st; i < en; ++i) {
        int u = csr[i];                      // uniform across wave (broadcast)
        float w = __expf(leaky(sS[u] + sdv) - m);
        float2 hu = *(const float2*)&H[(size_t)u * D + ch];
        accx += w * hu.x; accy += w * hu.y;
    }
    float inv = 1.0f / l;
    float2 bb = *(const float2*)&b[ch];
    float2 o;
    o.x = fmaxf(accx * inv + bb.x, 0.f);
    o.y = fmaxf(accy * inv + bb.y, 0.f);
    *(float2*)&O[(size_t)v * D + ch] = o;
}

// ---------------- launch ----------------

extern "C" void kernel_launch(void* const* d_in, const int* in_sizes, int n_in,
                              void* d_out, int out_size, void* d_ws, size_t ws_size,
                              hipStream_t stream) {
    const float* x  = (const float*)d_in[0];
    const int*   ei = (const int*)d_in[1];
    const float* Ws = (const float*)d_in[2];
    const float* bs = (const float*)d_in[3];
    const float* aS = (const float*)d_in[4];
    const float* aD = (const float*)d_in[5];
    float* out = (float*)d_out;

    int N = in_sizes[0] / D;
    int E = in_sizes[1] / 2;
    int L = in_sizes[2] / (D * D);

    char* w = (char*)d_ws;
    auto alloc = [&](size_t bytes) { char* p = w; w += (bytes + 255) & ~(size_t)255; return p; };
    int*   cursor   = (int*)alloc((size_t)N * 4);
    int*   rowptr   = (int*)alloc((size_t)(N + 1) * 4);
    int*   partial  = (int*)alloc(256 * 4);
    int*   chunkoff = (int*)alloc(256 * 4);
    int*   csr      = (int*)alloc((size_t)E * 4);
    float* sS       = (float*)alloc((size_t)N * 4);
    float* sD       = (float*)alloc((size_t)N * 4);
    float* H        = (float*)alloc((size_t)N * D * 4);
    // NOTE: intermediate layer outputs live in d_out (kernels serialize on the
    // stream: next layer's GEMM fully reads d_out before agg overwrites it).
    // Keeps workspace ~59MB instead of ~110MB.

    hipMemsetAsync(cursor, 0, (size_t)N * 4, stream);
    int nch = (N + 511) / 512;
    gat_count_deg<<<(E + 255) / 256, 256, 0, stream>>>(ei, cursor, E);
    gat_chunk_sum<<<nch, 256, 0, stream>>>(cursor, partial, N);
    gat_scan_partials<<<1, 256, 0, stream>>>(partial, chunkoff, rowptr, nch, N);
    gat_chunk_scan<<<nch, 256, 0, stream>>>(cursor, rowptr, chunkoff, N);
    gat_scatter<<<(E + 255) / 256, 256, 0, stream>>>(ei, cursor, csr, E);

    const float* in = x;
    for (int l = 0; l < L; ++l) {
        gat_gemm_s<<<(N + 63) / 64, 256, 0, stream>>>(
            in, Ws + (size_t)l * D * D, aS + (size_t)l * D, aD + (size_t)l * D,
            H, sS, sD, N);
        gat_agg<<<(N + 3) / 4, 256, 0, stream>>>(H, rowptr, csr, sS, sD,
                                                 bs + (size_t)l * D, out, N);
        in = out;
    }
}

// Round 6
// 810.519 us; speedup vs baseline: 1.2612x; 1.2612x over previous
//
#include <hip/hip_runtime.h>
#include <hip/hip_bf16.h>
#include <cstdint>
#include <cstddef>

#define D 128
#define NEG_SLOPE 0.2f

__device__ __forceinline__ float leaky(float x) { return x > 0.f ? x : NEG_SLOPE * x; }

// ---------------- CSR build ----------------

__global__ void gat_count_deg(const int* __restrict__ ei, int* __restrict__ cursor, int E) {
    int e = blockIdx.x * 256 + threadIdx.x;
    if (e < E) atomicAdd(&cursor[ei[E + e]], 1);
}

__global__ void gat_chunk_sum(const int* __restrict__ deg, int* __restrict__ partial, int n) {
    __shared__ int sm[256];
    int t = threadIdx.x, base = blockIdx.x * 512;
    int s = 0;
    if (base + t < n)       s += deg[base + t];
    if (base + 256 + t < n) s += deg[base + 256 + t];
    sm[t] = s; __syncthreads();
    for (int off = 128; off; off >>= 1) { if (t < off) sm[t] += sm[t + off]; __syncthreads(); }
    if (t == 0) partial[blockIdx.x] = sm[0];
}

// single block; assumes nchunks <= 256 (N=100000 -> 196 chunks)
__global__ void gat_scan_partials(const int* __restrict__ partial, int* __restrict__ chunkoff,
                                  int* __restrict__ rowptr, int nchunks, int n) {
    __shared__ int sm[256];
    int t = threadIdx.x;
    int v = (t < nchunks) ? partial[t] : 0;
    sm[t] = v; __syncthreads();
    for (int off = 1; off < 256; off <<= 1) {
        int x = (t >= off) ? sm[t - off] : 0;
        __syncthreads();
        sm[t] += x;
        __syncthreads();
    }
    chunkoff[t] = sm[t] - v;           // exclusive
    if (t == 255) rowptr[n] = sm[255]; // total edge count
}

__global__ void gat_chunk_scan(int* __restrict__ cursor, int* __restrict__ rowptr,
                               const int* __restrict__ chunkoff, int n) {
    __shared__ int sm[256];
    int t = threadIdx.x, base = blockIdx.x * 512;
    int i0 = base + 2 * t, i1 = i0 + 1;
    int d0 = (i0 < n) ? cursor[i0] : 0;
    int d1 = (i1 < n) ? cursor[i1] : 0;
    int s = d0 + d1;
    sm[t] = s; __syncthreads();
    for (int off = 1; off < 256; off <<= 1) {
        int x = (t >= off) ? sm[t - off] : 0;
        __syncthreads();
        sm[t] += x;
        __syncthreads();
    }
    int excl = sm[t] - s + chunkoff[blockIdx.x];
    if (i0 < n) { rowptr[i0] = excl;      cursor[i0] = excl; }
    if (i1 < n) { rowptr[i1] = excl + d0; cursor[i1] = excl + d0; }
}

__global__ void gat_scatter(const int* __restrict__ ei, int* __restrict__ cursor,
                            int* __restrict__ csr, int E) {
    int e = blockIdx.x * 256 + threadIdx.x;
    if (e < E) {
        int s = ei[e], d = ei[E + e];
        int p = atomicAdd(&cursor[d], 1);
        csr[p] = s;
    }
}

// ---------------- fp32 GEMM: H = A @ W, fused s_src/s_dst epilogue ----------------
// block: 256 threads; BM=64 rows x BN=128 (full width); BK=32
// thread (tn = t&15, tm = t>>4) computes rows tm*4..tm*4+3, cols tn*8..tn*8+7
__launch_bounds__(256)
__global__ void gat_gemm_s(const float* __restrict__ A, const float* __restrict__ W,
                           const float* __restrict__ aS, const float* __restrict__ aD,
                           float* __restrict__ H, float* __restrict__ sS, float* __restrict__ sD,
                           int n) {
    __shared__ float At[32][68];   // [k][row], padded, 16B-aligned rows
    __shared__ float Wt[32][136];  // [k][col], padded, 16B-aligned rows
    int t = threadIdx.x;
    int tn = t & 15, tm = t >> 4;
    int r0 = blockIdx.x * 64;

    float c[4][8];
#pragma unroll
    for (int r = 0; r < 4; ++r)
#pragma unroll
        for (int j = 0; j < 8; ++j) c[r][j] = 0.f;

    for (int k0 = 0; k0 < D; k0 += 32) {
        // A tile (64x32), stored transposed
        int row = t >> 3;
        int c4 = (t & 7) * 4;
#pragma unroll
        for (int h = 0; h < 2; ++h) {
            int rr = row + h * 32;
            int gr = r0 + rr;
            float4 v;
            if (gr < n) v = *(const float4*)&A[(size_t)gr * D + k0 + c4];
            else { v.x = v.y = v.z = v.w = 0.f; }
            At[c4 + 0][rr] = v.x; At[c4 + 1][rr] = v.y;
            At[c4 + 2][rr] = v.z; At[c4 + 3][rr] = v.w;
        }
        // W tile (32x128)
#pragma unroll
        for (int i = 0; i < 4; ++i) {
            int idx = t + i * 256;
            int k = idx >> 5;
            int cw = (idx & 31) * 4;
            *(float4*)&Wt[k][cw] = *(const float4*)&W[(size_t)(k0 + k) * D + cw];
        }
        __syncthreads();
#pragma unroll
        for (int kk = 0; kk < 32; ++kk) {
            float4 a4 = *(const float4*)&At[kk][tm * 4];
            float4 b0 = *(const float4*)&Wt[kk][tn * 8];
            float4 b1 = *(const float4*)&Wt[kk][tn * 8 + 4];
            float a_[4] = {a4.x, a4.y, a4.z, a4.w};
            float b_[8] = {b0.x, b0.y, b0.z, b0.w, b1.x, b1.y, b1.z, b1.w};
#pragma unroll
            for (int r = 0; r < 4; ++r)
#pragma unroll
                for (int j = 0; j < 8; ++j) c[r][j] += a_[r] * b_[j];
        }
        __syncthreads();
    }

    // epilogue: store H + per-row dot with a_src/a_dst
    float as_[8], ad_[8];
#pragma unroll
    for (int j = 0; j < 8; ++j) { as_[j] = aS[tn * 8 + j]; ad_[j] = aD[tn * 8 + j]; }
    float pS[4], pD[4];
#pragma unroll
    for (int r = 0; r < 4; ++r) {
        int gr = r0 + tm * 4 + r;
        pS[r] = 0.f; pD[r] = 0.f;
#pragma unroll
        for (int j = 0; j < 8; ++j) { pS[r] += as_[j] * c[r][j]; pD[r] += ad_[j] * c[r][j]; }
        if (gr < n) {
            float4 v0; v0.x = c[r][0]; v0.y = c[r][1]; v0.z = c[r][2]; v0.w = c[r][3];
            float4 v1; v1.x = c[r][4]; v1.y = c[r][5]; v1.z = c[r][6]; v1.w = c[r][7];
            *(float4*)&H[(size_t)gr * D + tn * 8]     = v0;
            *(float4*)&H[(size_t)gr * D + tn * 8 + 4] = v1;
        }
    }
#pragma unroll
    for (int off = 1; off < 16; off <<= 1) {
#pragma unroll
        for (int r = 0; r < 4; ++r) {
            pS[r] += __shfl_xor(pS[r], off);
            pD[r] += __shfl_xor(pD[r], off);
        }
    }
    if (tn == 0) {
#pragma unroll
        for (int r = 0; r < 4; ++r) {
            int gr = r0 + tm * 4 + r;
            if (gr < n) { sS[gr] = pS[r]; sD[gr] = pD[r]; }
        }
    }
}

// ---------------- aggregation: one wave per destination node ----------------
// Edge metadata (u, w) kept in registers, one edge per lane per 64-edge chunk.
// Gather loop gets u_j/w_j via __shfl (no memory) and is unrolled x4 into 4
// accumulator pairs -> 4 H-row loads (4x512B/wave) in flight.
__launch_bounds__(256)
__global__ void gat_agg(const float* __restrict__ H, const int* __restrict__ rowptr,
                        const int* __restrict__ csr, const float* __restrict__ sS,
                        const float* __restrict__ sD, const float* __restrict__ b,
                        float* __restrict__ O, int n) {
    int v = blockIdx.x * 4 + (threadIdx.x >> 6);
    if (v >= n) return;
    int lane = threadIdx.x & 63;
    int st = rowptr[v], en = rowptr[v + 1];
    float sdv = sD[v];
    float aself = leaky(sS[v] + sdv);

    // chunk 0 metadata: one edge per lane, kept live for reuse
    int i0 = st + lane;
    int u0 = (i0 < en) ? csr[i0] : 0;
    float s0 = (i0 < en) ? leaky(sS[u0] + sdv) : -3e38f;

    // max over all edges + self
    float m = fmaxf(aself, s0);
    for (int i = i0 + 64; i < en; i += 64) {
        int u = csr[i];
        m = fmaxf(m, leaky(sS[u] + sdv));
    }
#pragma unroll
    for (int off = 32; off; off >>= 1) m = fmaxf(m, __shfl_xor(m, off));

    // chunk 0 weights + denominator start
    float w0 = (i0 < en) ? __expf(s0 - m) : 0.f;
    float wself = __expf(aself - m);
    float t = w0;
#pragma unroll
    for (int off = 32; off; off >>= 1) t += __shfl_xor(t, off);
    float l = wself + t;

    int ch = lane * 2;
    float2 hv = *(const float2*)&H[(size_t)v * D + ch];
    float ax0 = wself * hv.x, ay0 = wself * hv.y;
    float ax1 = 0.f, ay1 = 0.f, ax2 = 0.f, ay2 = 0.f, ax3 = 0.f, ay3 = 0.f;

    // gather chunk 0
    int cn = en - st; if (cn > 64) cn = 64;
    int j = 0;
    for (; j + 4 <= cn; j += 4) {
        int uu0 = __shfl(u0, j),     uu1 = __shfl(u0, j + 1);
        int uu2 = __shfl(u0, j + 2), uu3 = __shfl(u0, j + 3);
        float ww0 = __shfl(w0, j),     ww1 = __shfl(w0, j + 1);
        float ww2 = __shfl(w0, j + 2), ww3 = __shfl(w0, j + 3);
        float2 h0 = *(const float2*)&H[(size_t)uu0 * D + ch];
        float2 h1 = *(const float2*)&H[(size_t)uu1 * D + ch];
        float2 h2 = *(const float2*)&H[(size_t)uu2 * D + ch];
        float2 h3 = *(const float2*)&H[(size_t)uu3 * D + ch];
        ax0 += ww0 * h0.x; ay0 += ww0 * h0.y;
        ax1 += ww1 * h1.x; ay1 += ww1 * h1.y;
        ax2 += ww2 * h2.x; ay2 += ww2 * h2.y;
        ax3 += ww3 * h3.x; ay3 += ww3 * h3.y;
    }
    for (; j < cn; ++j) {
        int uu = __shfl(u0, j);
        float ww = __shfl(w0, j);
        float2 hu = *(const float2*)&H[(size_t)uu * D + ch];
        ax0 += ww * hu.x; ay0 += ww * hu.y;
    }

    // rare: nodes with degree > 64, chunked
    for (int c = st + 64; c < en; c += 64) {
        int i = c + lane;
        int u = (i < en) ? csr[i] : 0;
        float s = (i < en) ? leaky(sS[u] + sdv) : 0.f;
        float w = (i < en) ? __expf(s - m) : 0.f;
        float tt = w;
#pragma unroll
        for (int off = 32; off; off >>= 1) tt += __shfl_xor(tt, off);
        l += tt;
        int cc = en - c; if (cc > 64) cc = 64;
        int k = 0;
        for (; k + 4 <= cc; k += 4) {
            int uu0 = __shfl(u, k),     uu1 = __shfl(u, k + 1);
            int uu2 = __shfl(u, k + 2), uu3 = __shfl(u, k + 3);
            float ww0 = __shfl(w, k),     ww1 = __shfl(w, k + 1);
            float ww2 = __shfl(w, k + 2), ww3 = __shfl(w, k + 3);
            float2 h0 = *(const float2*)&H[(size_t)uu0 * D + ch];
            float2 h1 = *(const float2*)&H[(size_t)uu1 * D + ch];
            float2 h2 = *(const float2*)&H[(size_t)uu2 * D + ch];
            float2 h3 = *(const float2*)&H[(size_t)uu3 * D + ch];
            ax0 += ww0 * h0.x; ay0 += ww0 * h0.y;
            ax1 += ww1 * h1.x; ay1 += ww1 * h1.y;
            ax2 += ww2 * h2.x; ay2 += ww2 * h2.y;
            ax3 += ww3 * h3.x; ay3 += ww3 * h3.y;
        }
        for (; k < cc; ++k) {
            int uu = __shfl(u, k);
            float ww = __shfl(w, k);
            float2 hu = *(const float2*)&H[(size_t)uu * D + ch];
            ax0 += ww * hu.x; ay0 += ww * hu.y;
        }
    }

    float accx = (ax0 + ax1) + (ax2 + ax3);
    float accy = (ay0 + ay1) + (ay2 + ay3);
    float inv = 1.0f / l;
    float2 bb = *(const float2*)&b[ch];
    float2 o;
    o.x = fmaxf(accx * inv + bb.x, 0.f);
    o.y = fmaxf(accy * inv + bb.y, 0.f);
    *(float2*)&O[(size_t)v * D + ch] = o;
}

// ---------------- launch ----------------

extern "C" void kernel_launch(void* const* d_in, const int* in_sizes, int n_in,
                              void* d_out, int out_size, void* d_ws, size_t ws_size,
                              hipStream_t stream) {
    const float* x  = (const float*)d_in[0];
    const int*   ei = (const int*)d_in[1];
    const float* Ws = (const float*)d_in[2];
    const float* bs = (const float*)d_in[3];
    const float* aS = (const float*)d_in[4];
    const float* aD = (const float*)d_in[5];
    float* out = (float*)d_out;

    int N = in_sizes[0] / D;
    int E = in_sizes[1] / 2;
    int L = in_sizes[2] / (D * D);

    char* w = (char*)d_ws;
    auto alloc = [&](size_t bytes) { char* p = w; w += (bytes + 255) & ~(size_t)255; return p; };
    int*   cursor   = (int*)alloc((size_t)N * 4);
    int*   rowptr   = (int*)alloc((size_t)(N + 1) * 4);
    int*   partial  = (int*)alloc(256 * 4);
    int*   chunkoff = (int*)alloc(256 * 4);
    int*   csr      = (int*)alloc((size_t)E * 4);
    float* sS       = (float*)alloc((size_t)N * 4);
    float* sD       = (float*)alloc((size_t)N * 4);
    float* H        = (float*)alloc((size_t)N * D * 4);
    // intermediate layer outputs live in d_out (stream-serialized, safe)

    hipMemsetAsync(cursor, 0, (size_t)N * 4, stream);
    int nch = (N + 511) / 512;
    gat_count_deg<<<(E + 255) / 256, 256, 0, stream>>>(ei, cursor, E);
    gat_chunk_sum<<<nch, 256, 0, stream>>>(cursor, partial, N);
    gat_scan_partials<<<1, 256, 0, stream>>>(partial, chunkoff, rowptr, nch, N);
    gat_chunk_scan<<<nch, 256, 0, stream>>>(cursor, rowptr, chunkoff, N);
    gat_scatter<<<(E + 255) / 256, 256, 0, stream>>>(ei, cursor, csr, E);

    const float* in = x;
    for (int l = 0; l < L; ++l) {
        gat_gemm_s<<<(N + 63) / 64, 256, 0, stream>>>(
            in, Ws + (size_t)l * D * D, aS + (size_t)l * D, aD + (size_t)l * D,
            H, sS, sD, N);
        gat_agg<<<(N + 3) / 4, 256, 0, stream>>>(H, rowptr, csr, sS, sD,
                                                 bs + (size_t)l * D, out, N);
        in = out;
    }
}

// Round 14
// 710.896 us; speedup vs baseline: 1.4379x; 1.1401x over previous
//
#include <hip/hip_runtime.h>
#include <hip/hip_bf16.h>
#include <cstdint>
#include <cstddef>

#define D 128
#define NEG_SLOPE 0.2f
#define NBMAX 128      // max buckets supported (N <= 131072)
#define BSH 10         // 1024 dst-nodes per bucket
#define CPAD 16        // counter padding in ints (64B) to spread atomic lines

__device__ __forceinline__ float leaky(float x) { return x > 0.f ? x : NEG_SLOPE * x; }

// ---------------- CSR build: bucketed counting sort (write-once csr) --------

// K1: per-bucket histogram
__global__ void gat_hist(const int* __restrict__ ei, int* __restrict__ gcount,
                         int E, int NB) {
    __shared__ int h[NBMAX];
    int t = threadIdx.x;
    if (t < NBMAX) h[t] = 0;
    __syncthreads();
    for (int e = blockIdx.x * 256 + t; e < E; e += gridDim.x * 256)
        atomicAdd(&h[ei[E + e] >> BSH], 1);
    __syncthreads();
    if (t < NB && h[t]) atomicAdd(&gcount[t * CPAD], h[t]);
}

// K2: bucket bases + cursor init + rowptr[N]=E (serial over <=128 buckets)
__global__ void gat_bases(const int* __restrict__ gcount, int* __restrict__ bases,
                          int* __restrict__ cursor, int* __restrict__ rowptr,
                          int NB, int N, int E) {
    if (threadIdx.x == 0) {
        int s = 0;
        for (int b = 0; b < NB; ++b) {
            bases[b] = s;
            cursor[b * CPAD] = s;
            s += gcount[b * CPAD];
        }
        rowptr[N] = E;
    }
}

// K3: bucketize edges; one 2048-edge batch per workgroup; range claimed per
// bucket per batch with a single global atomic -> dense staging writes.
__launch_bounds__(256)
__global__ void gat_bucket(const int* __restrict__ ei, int* __restrict__ cursor,
                           int* __restrict__ stg, int E) {
    __shared__ int hist[NBMAX], lcur[NBMAX], rbase[NBMAX];
    int t = threadIdx.x;
    int e0 = blockIdx.x * 2048;
    if (t < NBMAX) hist[t] = 0;
    __syncthreads();
    int pk[8], bk[8];
#pragma unroll
    for (int j = 0; j < 8; ++j) {
        int e = e0 + t + j * 256;
        if (e < E) {
            int s = ei[e], d = ei[E + e];
            bk[j] = d >> BSH;
            pk[j] = s | ((d & ((1 << BSH) - 1)) << 17);
            atomicAdd(&hist[bk[j]], 1);
        } else bk[j] = -1;
    }
    __syncthreads();
    if (t < NBMAX) {
        lcur[t] = 0;
        if (hist[t]) rbase[t] = atomicAdd(&cursor[t * CPAD], hist[t]);
    }
    __syncthreads();
#pragma unroll
    for (int j = 0; j < 8; ++j) {
        if (bk[j] >= 0) {
            int p = rbase[bk[j]] + atomicAdd(&lcur[bk[j]], 1);
            stg[p] = pk[j];
        }
    }
}

// K4: per-bucket counting sort: LDS degree count -> scan -> rowptr + csr.
// All csr writes for a bucket come from ONE workgroup -> L2-merged, written once.
__launch_bounds__(256)
__global__ void gat_build(const int* __restrict__ stg, const int* __restrict__ gcount,
                          const int* __restrict__ bases, int* __restrict__ rowptr,
                          int* __restrict__ csr, int N) {
    __shared__ int deg[1 << BSH];
    __shared__ int cur[1 << BSH];
    __shared__ int part[256];
    int b = blockIdx.x, t = threadIdx.x;
    int base = bases[b], cnt = gcount[b * CPAD];
#pragma unroll
    for (int j = 0; j < (1 << BSH) / 256; ++j) deg[t + j * 256] = 0;
    __syncthreads();
    for (int i = t; i < cnt; i += 256) atomicAdd(&deg[stg[base + i] >> 17], 1);
    __syncthreads();
    int d0 = deg[t * 4], d1 = deg[t * 4 + 1], d2 = deg[t * 4 + 2], d3 = deg[t * 4 + 3];
    int tsum = d0 + d1 + d2 + d3;
    part[t] = tsum; __syncthreads();
    for (int off = 1; off < 256; off <<= 1) {
        int x = (t >= off) ? part[t - off] : 0;
        __syncthreads();
        part[t] += x;
        __syncthreads();
    }
    int ex = part[t] - tsum;
    int e0 = ex, e1 = ex + d0, e2 = e1 + d1, e3 = e2 + d2;
    cur[t * 4] = e0; cur[t * 4 + 1] = e1; cur[t * 4 + 2] = e2; cur[t * 4 + 3] = e3;
    int nb0 = b << BSH;
    if (nb0 + t * 4     < N) rowptr[nb0 + t * 4]     = base + e0;
    if (nb0 + t * 4 + 1 < N) rowptr[nb0 + t * 4 + 1] = base + e1;
    if (nb0 + t * 4 + 2 < N) rowptr[nb0 + t * 4 + 2] = base + e2;
    if (nb0 + t * 4 + 3 < N) rowptr[nb0 + t * 4 + 3] = base + e3;
    __syncthreads();
    for (int i = t; i < cnt; i += 256) {
        int e = stg[base + i];
        int p = atomicAdd(&cur[e >> 17], 1);
        csr[base + p] = e & 0x1FFFF;
    }
}

// ---------------- fp32 GEMM: H = A @ W, fused s_src/s_dst epilogue ----------------
__launch_bounds__(256)
__global__ void gat_gemm_s(const float* __restrict__ A, const float* __restrict__ W,
                           const float* __restrict__ aS, const float* __restrict__ aD,
                           float* __restrict__ H, float* __restrict__ sS, float* __restrict__ sD,
                           int n) {
    __shared__ float At[32][68];
    __shared__ float Wt[32][136];
    int t = threadIdx.x;
    int tn = t & 15, tm = t >> 4;
    int r0 = blockIdx.x * 64;

    float c[4][8];
#pragma unroll
    for (int r = 0; r < 4; ++r)
#pragma unroll
        for (int j = 0; j < 8; ++j) c[r][j] = 0.f;

    for (int k0 = 0; k0 < D; k0 += 32) {
        int row = t >> 3;
        int c4 = (t & 7) * 4;
#pragma unroll
        for (int h = 0; h < 2; ++h) {
            int rr = row + h * 32;
            int gr = r0 + rr;
            float4 v;
            if (gr < n) v = *(const float4*)&A[(size_t)gr * D + k0 + c4];
            else { v.x = v.y = v.z = v.w = 0.f; }
            At[c4 + 0][rr] = v.x; At[c4 + 1][rr] = v.y;
            At[c4 + 2][rr] = v.z; At[c4 + 3][rr] = v.w;
        }
#pragma unroll
        for (int i = 0; i < 4; ++i) {
            int idx = t + i * 256;
            int k = idx >> 5;
            int cw = (idx & 31) * 4;
            *(float4*)&Wt[k][cw] = *(const float4*)&W[(size_t)(k0 + k) * D + cw];
        }
        __syncthreads();
#pragma unroll
        for (int kk = 0; kk < 32; ++kk) {
            float4 a4 = *(const float4*)&At[kk][tm * 4];
            float4 b0 = *(const float4*)&Wt[kk][tn * 8];
            float4 b1 = *(const float4*)&Wt[kk][tn * 8 + 4];
            float a_[4] = {a4.x, a4.y, a4.z, a4.w};
            float b_[8] = {b0.x, b0.y, b0.z, b0.w, b1.x, b1.y, b1.z, b1.w};
#pragma unroll
            for (int r = 0; r < 4; ++r)
#pragma unroll
                for (int j = 0; j < 8; ++j) c[r][j] += a_[r] * b_[j];
        }
        __syncthreads();
    }

    float as_[8], ad_[8];
#pragma unroll
    for (int j = 0; j < 8; ++j) { as_[j] = aS[tn * 8 + j]; ad_[j] = aD[tn * 8 + j]; }
    float pS[4], pD[4];
#pragma unroll
    for (int r = 0; r < 4; ++r) {
        int gr = r0 + tm * 4 + r;
        pS[r] = 0.f; pD[r] = 0.f;
#pragma unroll
        for (int j = 0; j < 8; ++j) { pS[r] += as_[j] * c[r][j]; pD[r] += ad_[j] * c[r][j]; }
        if (gr < n) {
            float4 v0; v0.x = c[r][0]; v0.y = c[r][1]; v0.z = c[r][2]; v0.w = c[r][3];
            float4 v1; v1.x = c[r][4]; v1.y = c[r][5]; v1.z = c[r][6]; v1.w = c[r][7];
            *(float4*)&H[(size_t)gr * D + tn * 8]     = v0;
            *(float4*)&H[(size_t)gr * D + tn * 8 + 4] = v1;
        }
    }
#pragma unroll
    for (int off = 1; off < 16; off <<= 1) {
#pragma unroll
        for (int r = 0; r < 4; ++r) {
            pS[r] += __shfl_xor(pS[r], off);
            pD[r] += __shfl_xor(pD[r], off);
        }
    }
    if (tn == 0) {
#pragma unroll
        for (int r = 0; r < 4; ++r) {
            int gr = r0 + tm * 4 + r;
            if (gr < n) { sS[gr] = pS[r]; sD[gr] = pD[r]; }
        }
    }
}

// ---------------- aggregation: one wave per destination node ----------------
__launch_bounds__(256)
__global__ void gat_agg(const float* __restrict__ H, const int* __restrict__ rowptr,
                        const int* __restrict__ csr, const float* __restrict__ sS,
                        const float* __restrict__ sD, const float* __restrict__ b,
                        float* __restrict__ O, int n) {
    int v = blockIdx.x * 4 + (threadIdx.x >> 6);
    if (v >= n) return;
    int lane = threadIdx.x & 63;
    int st = rowptr[v], en = rowptr[v + 1];
    float sdv = sD[v];
    float aself = leaky(sS[v] + sdv);

    int i0 = st + lane;
    int u0 = (i0 < en) ? csr[i0] : 0;
    float s0 = (i0 < en) ? leaky(sS[u0] + sdv) : -3e38f;

    float m = fmaxf(aself, s0);
    for (int i = i0 + 64; i < en; i += 64) {
        int u = csr[i];
        m = fmaxf(m, leaky(sS[u] + sdv));
    }
#pragma unroll
    for (int off = 32; off; off >>= 1) m = fmaxf(m, __shfl_xor(m, off));

    float w0 = (i0 < en) ? __expf(s0 - m) : 0.f;
    float wself = __expf(aself - m);
    float t = w0;
#pragma unroll
    for (int off = 32; off; off >>= 1) t += __shfl_xor(t, off);
    float l = wself + t;

    int ch = lane * 2;
    float2 hv = *(const float2*)&H[(size_t)v * D + ch];
    float ax0 = wself * hv.x, ay0 = wself * hv.y;
    float ax1 = 0.f, ay1 = 0.f, ax2 = 0.f, ay2 = 0.f, ax3 = 0.f, ay3 = 0.f;

    int cn = en - st; if (cn > 64) cn = 64;
    int j = 0;
    for (; j + 4 <= cn; j += 4) {
        int uu0 = __shfl(u0, j),     uu1 = __shfl(u0, j + 1);
        int uu2 = __shfl(u0, j + 2), uu3 = __shfl(u0, j + 3);
        float ww0 = __shfl(w0, j),     ww1 = __shfl(w0, j + 1);
        float ww2 = __shfl(w0, j + 2), ww3 = __shfl(w0, j + 3);
        float2 h0 = *(const float2*)&H[(size_t)uu0 * D + ch];
        float2 h1 = *(const float2*)&H[(size_t)uu1 * D + ch];
        float2 h2 = *(const float2*)&H[(size_t)uu2 * D + ch];
        float2 h3 = *(const float2*)&H[(size_t)uu3 * D + ch];
        ax0 += ww0 * h0.x; ay0 += ww0 * h0.y;
        ax1 += ww1 * h1.x; ay1 += ww1 * h1.y;
        ax2 += ww2 * h2.x; ay2 += ww2 * h2.y;
        ax3 += ww3 * h3.x; ay3 += ww3 * h3.y;
    }
    for (; j < cn; ++j) {
        int uu = __shfl(u0, j);
        float ww = __shfl(w0, j);
        float2 hu = *(const float2*)&H[(size_t)uu * D + ch];
        ax0 += ww * hu.x; ay0 += ww * hu.y;
    }

    for (int c = st + 64; c < en; c += 64) {
        int i = c + lane;
        int u = (i < en) ? csr[i] : 0;
        float s = (i < en) ? leaky(sS[u] + sdv) : 0.f;
        float w = (i < en) ? __expf(s - m) : 0.f;
        float tt = w;
#pragma unroll
        for (int off = 32; off; off >>= 1) tt += __shfl_xor(tt, off);
        l += tt;
        int cc = en - c; if (cc > 64) cc = 64;
        int k = 0;
        for (; k + 4 <= cc; k += 4) {
            int uu0 = __shfl(u, k),     uu1 = __shfl(u, k + 1);
            int uu2 = __shfl(u, k + 2), uu3 = __shfl(u, k + 3);
            float ww0 = __shfl(w, k),     ww1 = __shfl(w, k + 1);
            float ww2 = __shfl(w, k + 2), ww3 = __shfl(w, k + 3);
            float2 h0 = *(const float2*)&H[(size_t)uu0 * D + ch];
            float2 h1 = *(const float2*)&H[(size_t)uu1 * D + ch];
            float2 h2 = *(const float2*)&H[(size_t)uu2 * D + ch];
            float2 h3 = *(const float2*)&H[(size_t)uu3 * D + ch];
            ax0 += ww0 * h0.x; ay0 += ww0 * h0.y;
            ax1 += ww1 * h1.x; ay1 += ww1 * h1.y;
            ax2 += ww2 * h2.x; ay2 += ww2 * h2.y;
            ax3 += ww3 * h3.x; ay3 += ww3 * h3.y;
        }
        for (; k < cc; ++k) {
            int uu = __shfl(u, k);
            float ww = __shfl(w, k);
            float2 hu = *(const float2*)&H[(size_t)uu * D + ch];
            ax0 += ww * hu.x; ay0 += ww * hu.y;
        }
    }

    float accx = (ax0 + ax1) + (ax2 + ax3);
    float accy = (ay0 + ay1) + (ay2 + ay3);
    float inv = 1.0f / l;
    float2 bb = *(const float2*)&b[ch];
    float2 o;
    o.x = fmaxf(accx * inv + bb.x, 0.f);
    o.y = fmaxf(accy * inv + bb.y, 0.f);
    *(float2*)&O[(size_t)v * D + ch] = o;
}

// ---------------- launch ----------------

extern "C" void kernel_launch(void* const* d_in, const int* in_sizes, int n_in,
                              void* d_out, int out_size, void* d_ws, size_t ws_size,
                              hipStream_t stream) {
    const float* x  = (const float*)d_in[0];
    const int*   ei = (const int*)d_in[1];
    const float* Ws = (const float*)d_in[2];
    const float* bs = (const float*)d_in[3];
    const float* aS = (const float*)d_in[4];
    const float* aD = (const float*)d_in[5];
    float* out = (float*)d_out;

    int N = in_sizes[0] / D;
    int E = in_sizes[1] / 2;
    int L = in_sizes[2] / (D * D);
    int NB = (N + (1 << BSH) - 1) >> BSH;   // 98 for N=100000; must be <= NBMAX

    char* w = (char*)d_ws;
    auto alloc = [&](size_t bytes) { char* p = w; w += (bytes + 255) & ~(size_t)255; return p; };
    int*   gcount = (int*)alloc((size_t)NBMAX * CPAD * 4);
    int*   cursor = (int*)alloc((size_t)NBMAX * CPAD * 4);
    int*   bases  = (int*)alloc((size_t)NBMAX * 4);
    int*   rowptr = (int*)alloc((size_t)(N + 1) * 4);
    int*   csr    = (int*)alloc((size_t)E * 4);
    float* sS     = (float*)alloc((size_t)N * 4);
    float* sD     = (float*)alloc((size_t)N * 4);
    float* H      = (float*)alloc((size_t)N * D * 4);
    int*   stg    = (int*)H;   // staging aliases H: CSR build finishes before GEMM writes H

    hipMemsetAsync(gcount, 0, (size_t)NBMAX * CPAD * 4, stream);
    gat_hist  <<<512, 256, 0, stream>>>(ei, gcount, E, NB);
    gat_bases <<<1, 64, 0, stream>>>(gcount, bases, cursor, rowptr, NB, N, E);
    gat_bucket<<<(E + 2047) / 2048, 256, 0, stream>>>(ei, cursor, stg, E);
    gat_build <<<NB, 256, 0, stream>>>(stg, gcount, bases, rowptr, csr, N);

    const float* in = x;
    for (int l = 0; l < L; ++l) {
        gat_gemm_s<<<(N + 63) / 64, 256, 0, stream>>>(
            in, Ws + (size_t)l * D * D, aS + (size_t)l * D, aD + (size_t)l * D,
            H, sS, sD, N);
        gat_agg<<<(N + 3) / 4, 256, 0, stream>>>(H, rowptr, csr, sS, sD,
                                                 bs + (size_t)l * D, out, N);
        in = out;
    }
}